// Round 5
// baseline (451.628 us; speedup 1.0000x reference)
//
#include <hip/hip_runtime.h>
#include <hip/hip_bf16.h>
#include <hip/hip_fp8.h>

typedef __attribute__((ext_vector_type(4))) float f32x4;
typedef __attribute__((ext_vector_type(2))) long i64x2;

#define B_   16
#define C_   128
#define DIM  24
#define F_   128
#define OD   22
#define OS   (OD*OD*OD)        // 10648
#define SPB  (DIM*DIM*DIM)     // 13824 spatial per (b)
#define K_   3456              // 128*27
#define M_   (B_*OS)           // 170368
#define OUTN (B_*F_*OS)        // 21807104

// ---------------- async global->LDS (16B per lane, wave-uniform LDS base) ---
__device__ __forceinline__ void async16(const void* g, void* l) {
  __builtin_amdgcn_global_load_lds(
      (const __attribute__((address_space(1))) unsigned int*)g,
      (__attribute__((address_space(3))) unsigned int*)l, 16, 0, 0);
}

__device__ __forceinline__ unsigned char f2fp8(float v) {
  return __hip_fp8_e4m3(v).__x;            // OCP e4m3fn on gfx950
}

// ---------------- kernel 1: xs -> channels-last FP8 xt (k-permuted rows),
// plus s1 = sum_c x^2.  Row layout: channel c at byte pos q*32+kk*8+j where
// j=c&7, q=(c>>3)&3, kk=c>>5 -> GEMM fragment (q,kk) is a contiguous 8B run,
// and the b128 chunk (q*2+kkp) pairs kk=2kkp,2kkp+1.  8B-group permute only.
__global__ __launch_bounds__(256) void prep_x(const float* __restrict__ xs,
                                              unsigned char* __restrict__ xt,
                                              float* __restrict__ s1) {
  __shared__ float tile[C_ * 97];            // 49.7 KB
  __shared__ float red[192];
  const int blk = blockIdx.x;                // (b*24+z)*6+yg, 2304 blocks
  const int yg = blk % 6;
  const int t2 = blk / 6;
  const int z = t2 % DIM;
  const int b = t2 / DIM;
  const int t = threadIdx.x;
  const float* src = xs + (size_t)b * C_ * SPB + z * (DIM * DIM) + yg * 96;
  for (int it = 0; it < 12; ++it) {
    int idx = it * 256 + t;
    int c = idx / 24, f4 = idx - c * 24;
    const float4 v = *(const float4*)(src + (size_t)c * SPB + f4 * 4);
    float* d = &tile[c * 97 + f4 * 4];
    d[0] = v.x; d[1] = v.y; d[2] = v.z; d[3] = v.w;
  }
  __syncthreads();
  // store fp8: 96 positions x 16 slots of 8 channels (8B store per thread-iter)
  size_t obase = ((size_t)b * SPB + z * (DIM * DIM) + yg * 96) * C_;  // bytes
  for (int it = 0; it < 6; ++it) {
    int idx = it * 256 + t;
    int s = idx & 15, x = idx >> 4;
    int g = (s & 3) * 4 + (s >> 2);          // source 8-channel group for slot s
    unsigned int w0 = 0, w1 = 0;
#pragma unroll
    for (int j = 0; j < 4; ++j)
      w0 |= ((unsigned int)f2fp8(tile[(8 * g + j) * 97 + x])) << (8 * j);
#pragma unroll
    for (int j = 0; j < 4; ++j)
      w1 |= ((unsigned int)f2fp8(tile[(8 * g + 4 + j) * 97 + x])) << (8 * j);
    *(uint2*)&xt[obase + (size_t)x * C_ + s * 8] = make_uint2(w0, w1);
  }
  // s1: sum_c x^2 for the 96 positions (fp32, unchanged)
  if (t < 192) {
    int g = t / 96, p = t - g * 96;
    float s = 0.f;
    for (int c = g; c < C_; c += 2) {
      float v = tile[c * 97 + p];
      s += v * v;
    }
    red[g * 96 + p] = s;
  }
  __syncthreads();
  if (t < 96)
    s1[((size_t)b * SPB + z * (DIM * DIM) + yg * 96) + t] = red[t] + red[96 + t];
}

// ---------------- kernel 2: weights -> fp8 Wt[f][tap*128 + perm(c)] + ||p||^2
__global__ void prep_w(const float* __restrict__ fv,
                       unsigned char* __restrict__ Wt,
                       float* __restrict__ psq) {
  __shared__ float tile[K_];                 // 13.8 KB
  const int f = blockIdx.x;                  // 128 blocks
  const float* src = fv + (size_t)f * K_;
  float part = 0.f;
  for (int idx = threadIdx.x; idx < K_; idx += 256) {
    float v = src[idx];                      // coalesced
    tile[idx] = v;
    part += v * v;
  }
  __syncthreads();
  for (int idx = threadIdx.x; idx < K_; idx += 256) {
    int c = idx & 127, off = idx >> 7;
    int pos = off * 128 + ((c >> 3) & 3) * 32 + (c >> 5) * 8 + (c & 7);
    Wt[(size_t)f * K_ + pos] = f2fp8(tile[c * 27 + off]);
  }
  for (int o = 32; o > 0; o >>= 1) part += __shfl_down(part, o, 64);
  __shared__ float red[4];
  int w = threadIdx.x >> 6, l = threadIdx.x & 63;
  if (l == 0) red[w] = part;
  __syncthreads();
  if (threadIdx.x == 0) psq[f] = red[0] + red[1] + red[2] + red[3];
}

// ---------------- kernel 3: fp8 implicit-GEMM MFMA + fused pool + L2 epilogue
// R5: fp8 e4m3 operands, BK=128 = ONE conv tap per K-tile (27 tiles, was 54).
// Tile 128f x 256m, 4 waves, wave = 64f x 128m (R4's verified layout/epilogue).
// LDS: W 16KB + P 32KB + xsq 1KB = 49 KB -> 3 blocks/CU. Halves LDS bytes,
// staging bytes, VMEM instrs and barriers vs R4 at unchanged MFMA rate
// (fp8 16x16x32 = bf16 rate). Rows are 128B; 16B chunk e of row r lives at
// XOR slot e^(r&7); staging pre-swizzles the GLOBAL source chunk, reads
// apply the same XOR (byte-geometry identical to verified bf16 kernel).
// pool_sq is fused into the prologue (s1 is L2-resident, 27 reads/thread).
__global__ __launch_bounds__(256) void l2gemm(
    const unsigned char* __restrict__ xt, const unsigned char* __restrict__ Wt,
    const float* __restrict__ s1, const float* __restrict__ psq,
    float* __restrict__ out) {
  __shared__ __align__(16) unsigned char Wl[128 * 128];   // 16 KB
  __shared__ __align__(16) unsigned char Pl[256 * 128];   // 32 KB
  __shared__ float xsql[256];                              // 1 KB
  const int t = threadIdx.x;
  const int l = t & 63, w = t >> 6;          // 4 waves
  const int quad = l >> 4, lan = l & 15;
  const int e = t & 7, r0 = t >> 3;          // staging: chunk e of rows r0+32p
  const int esw = (e ^ (r0 & 7)) * 16;       // XOR-swizzled source chunk (bytes)

  // bijective XCD-aware block swizzle (nwg=666, 666%8!=0)
  const int nwg = gridDim.x;
  const int orig = blockIdx.x;
  const int xcd = orig & 7, lo = orig >> 3;
  const int q = nwg >> 3, r = nwg & 7;
  const int mt = (xcd < r ? xcd * (q + 1) : r * (q + 1) + (xcd - r) * q) + lo;

  // spatial base for the 8 staged patch rows (m = mt*256 + r0 + 32p), clamped
  int sb[8];
#pragma unroll
  for (int p = 0; p < 8; ++p) {
    int m = mt * 256 + r0 + 32 * p;
    if (m >= M_) m = M_ - 1;                 // tail block: safe duplicate gather
    int b = m / OS;
    int s = m - b * OS;
    int od = s / (OD * OD);
    int s2 = s - od * (OD * OD);
    int oh = s2 / OD;
    int ow = s2 - oh * OD;
    sb[p] = b * SPB + od * 576 + oh * 24 + ow;
  }

  // fused 3x3x3 sum-pool of s1 for this block's 256 m's (L2-resident reads)
  {
    int m = mt * 256 + t;
    if (m >= M_) m = M_ - 1;
    int b = m / OS;
    int s = m - b * OS;
    int od = s / (OD * OD);
    int s2 = s - od * (OD * OD);
    int oh = s2 / OD;
    int ow = s2 - oh * OD;
    const float* pp = s1 + ((b * DIM + od) * DIM + oh) * DIM + ow;
    float ss = 0.f;
#pragma unroll
    for (int dz = 0; dz < 3; ++dz)
#pragma unroll
      for (int dy = 0; dy < 3; ++dy)
#pragma unroll
        for (int dx = 0; dx < 3; ++dx)
          ss += pp[dz * 576 + dy * 24 + dx];
    xsql[t] = ss;
  }

  f32x4 acc[4][8];
#pragma unroll
  for (int i = 0; i < 4; ++i)
#pragma unroll
    for (int n = 0; n < 8; ++n) acc[i][n] = (f32x4){0.f, 0.f, 0.f, 0.f};

  const int wm = (w & 1) * 64;    // f-offset of this wave's 64f x 128m subtile
  const int wn = (w >> 1) * 128;  // m-offset in [0,256)

#pragma unroll 1
  for (int kt = 0; kt < 27; ++kt) {
    // ---- stage tap kt: 12 x global_load_lds_dwordx4 per thread ----
    {
      int dz = kt / 9;
      int rem = kt - dz * 9;
      int dy = rem / 3;
      int dx = rem - dy * 3;
      int doff = dz * 576 + dy * 24 + dx;
#pragma unroll
      for (int p = 0; p < 4; ++p) {          // W: 128 rows x 128B
        const unsigned char* gw = Wt + (size_t)(r0 + 32 * p) * K_ + kt * 128 + esw;
        async16(gw, &Wl[(size_t)(8 * w + 32 * p) * 128]);
      }
#pragma unroll
      for (int p = 0; p < 8; ++p) {          // P: 256 rows x 128B (gathered)
        const unsigned char* gp = xt + (size_t)(sb[p] + doff) * 128 + esw;
        async16(gp, &Pl[(size_t)(8 * w + 32 * p) * 128]);
      }
    }
    __syncthreads();                         // drain vmcnt(0): tap ready
    // ---- compute: K=128 as 2 b128-pairs x 2 halves, 128 MFMA/wave ----
#pragma unroll
    for (int kkp = 0; kkp < 2; ++kkp) {
      const int swz = (((quad << 1) | kkp) ^ (lan & 7)) * 16;  // read-side XOR
      i64x2 a2[4], b2[8];
#pragma unroll
      for (int i = 0; i < 4; ++i)
        a2[i] = *(const i64x2*)&Wl[(wm + i * 16 + lan) * 128 + swz];
#pragma unroll
      for (int n = 0; n < 8; ++n)
        b2[n] = *(const i64x2*)&Pl[(wn + n * 16 + lan) * 128 + swz];
      __builtin_amdgcn_s_setprio(1);
#pragma unroll
      for (int h = 0; h < 2; ++h)
#pragma unroll
        for (int i = 0; i < 4; ++i)
#pragma unroll
          for (int n = 0; n < 8; ++n)
            acc[i][n] = __builtin_amdgcn_mfma_f32_16x16x32_fp8_fp8(
                a2[i][h], b2[n][h], acc[i][n], 0, 0, 0);
      __builtin_amdgcn_s_setprio(0);
    }
    __syncthreads();                         // all reads done before next stage
  }

  // epilogue: out[b][f][s] = sqrt(|xsq + psq - 2*dot| + eps)
  int mb[8], mok[8];
  float xv[8];
#pragma unroll
  for (int n = 0; n < 8; ++n) {
    int m = mt * 256 + wn + n * 16 + lan;
    mok[n] = (m < M_);
    if (m >= M_) m = M_ - 1;
    int b = m / OS;
    int s = m - b * OS;
    mb[n] = b * (F_ * OS) + s;
    xv[n] = xsql[wn + n * 16 + lan];
  }
#pragma unroll
  for (int i = 0; i < 4; ++i) {
#pragma unroll
    for (int r2 = 0; r2 < 4; ++r2) {
      int f = wm + i * 16 + quad * 4 + r2;
      float pq = psq[f];
#pragma unroll
      for (int n = 0; n < 8; ++n) {
        if (mok[n]) {
          float d = xv[n] + pq - 2.0f * acc[i][n][r2];
          out[mb[n] + f * OS] = sqrtf(fabsf(d) + 1e-14f);
        }
      }
    }
  }
}

// ---------------- fallback: direct fp32 conv (only if ws too small) ---------
__global__ void l2conv_direct(const float* __restrict__ xs,
                              const float* __restrict__ fv,
                              float* __restrict__ out) {
  int i = blockIdx.x * 256 + threadIdx.x;
  if (i >= OUTN) return;
  int s = i % OS;
  int t2 = i / OS;
  int f = t2 & 127;
  int b = t2 >> 7;
  int od = s / (OD * OD);
  int s2 = s - od * (OD * OD);
  int oh = s2 / OD;
  int ow = s2 - oh * OD;
  const float* xp = xs + (size_t)b * C_ * SPB + od * 576 + oh * 24 + ow;
  const float* wp = fv + (size_t)f * K_;
  float dot = 0.f, xq = 0.f, pq = 0.f;
  for (int c = 0; c < C_; ++c) {
    const float* xpc = xp + (size_t)c * SPB;
    const float* wpc = wp + c * 27;
#pragma unroll
    for (int o = 0; o < 27; ++o) {
      int dz = o / 9;
      int ry = o - dz * 9;
      int dy = ry / 3;
      int dx = ry - dy * 3;
      float xv = xpc[dz * 576 + dy * 24 + dx];
      float wv = wpc[o];
      dot += xv * wv;
      xq += xv * xv;
      pq += wv * wv;
    }
  }
  out[i] = sqrtf(fabsf(xq + pq - 2.f * dot) + 1e-14f);
}

// ---------------- launch ----------------------------------------------------
extern "C" void kernel_launch(void* const* d_in, const int* in_sizes, int n_in,
                              void* d_out, int out_size, void* d_ws,
                              size_t ws_size, hipStream_t stream) {
  const float* xs = (const float*)d_in[0];
  const float* fv = (const float*)d_in[1];
  float* out = (float*)d_out;

  const size_t xt_b  = (size_t)B_ * SPB * C_;       // 28,311,552 (fp8)
  const size_t wt_b  = (size_t)F_ * K_;             //    442,368 (fp8)
  const size_t s1_b  = (size_t)B_ * SPB * 4;        //    884,736
  const size_t psq_b = 512;
  if (ws_size < xt_b + wt_b + s1_b + psq_b) {
    l2conv_direct<<<(OUTN + 255) / 256, 256, 0, stream>>>(xs, fv, out);
    return;
  }
  char* p = (char*)d_ws;
  unsigned char* xt = (unsigned char*)p;  p += xt_b;
  unsigned char* Wt = (unsigned char*)p;  p += wt_b;
  float* s1 = (float*)p;                  p += s1_b;
  float* psq = (float*)p;

  prep_x<<<B_ * DIM * DIM / 4, 256, 0, stream>>>(xs, xt, s1);
  prep_w<<<F_, 256, 0, stream>>>(fv, Wt, psq);
  l2gemm<<<(M_ + 255) / 256, 256, 0, stream>>>(xt, Wt, s1, psq, out);
}